// Round 14
// baseline (39.695 us; speedup 1.0000x reference)
//
#include <hip/hip_runtime.h>

#define NUM_SAMPLES 64
#define HIDDEN 64
#define Z_NEAR 2.0f
#define Z_FAR 6.0f
#define LOG2E 1.44269504088896f

typedef _Float16 half8 __attribute__((ext_vector_type(8)));
typedef __fp16  fp16x2 __attribute__((ext_vector_type(2)));
typedef float   float4t __attribute__((ext_vector_type(4)));

// DPP add helper (bound_ctrl: out-of-range reads as 0).
template<int CTRL, int RMASK>
__device__ __forceinline__ float dpp_add(float x) {
    const int m = __builtin_amdgcn_update_dpp(0, __float_as_int(x), CTRL, RMASK, 0xf, true);
    return x + __int_as_float(m);
}
// 4-step inclusive add-scan within each 16-lane row (lane15 = row total).
__device__ __forceinline__ float row_scan_add(float x) {
    x = dpp_add<0x111, 0xf>(x);   // row_shr:1
    x = dpp_add<0x112, 0xf>(x);   // row_shr:2
    x = dpp_add<0x114, 0xf>(x);   // row_shr:4
    x = dpp_add<0x118, 0xf>(x);   // row_shr:8
    return x;
}

// R9 (28.2us, verified) with the cst LDS round-trip DELETED:
// after swapped MFMA, lanes 0-15 already hold all 4 outputs of sample
// 16m+col per tile m in registers; composite runs on 16 lanes with
// 4 samples/lane (4 independent 4-step row scans + readlane block offsets)
// instead of redistributing to 64 lanes through LDS. No barriers.
__global__ __launch_bounds__(256) void render_kernel(
    const float* __restrict__ cam,    // 4x4
    const float* __restrict__ u,      // R x S
    const float* __restrict__ cdirs,  // R x 3
    const float* __restrict__ W1,     // 6 x 64
    const float* __restrict__ b1,     // 64
    const float* __restrict__ W2,     // 64 x 4
    const float* __restrict__ b2,     // 4
    float* __restrict__ out)          // R x 3
{
    const int lane = threadIdx.x & 63;
    const int wid  = threadIdx.x >> 6;
    const int ray  = blockIdx.x * 4 + wid;
    const int grp  = lane >> 4;       // k-group
    const int col  = lane & 15;       // sample-in-tile

    __shared__ __align__(16) __fp16 Ahsh[4][HIDDEN];
    __shared__ __align__(16) __fp16 Bhsh[4][HIDDEN];
    __shared__ __align__(16) float  tsh[4][NUM_SAMPLES];
    __shared__ __align__(16) __fp16 W2T[4][4][80];   // fp16 W2^T, padded rows

    // per-wave fp16 W2^T staging (lane = hidden unit h)
    {
        const float4 w2row = ((const float4*)W2)[lane];
        W2T[wid][0][lane] = (__fp16)w2row.x;
        W2T[wid][1][lane] = (__fp16)w2row.y;
        W2T[wid][2][lane] = (__fp16)w2row.z;
        W2T[wid][3][lane] = (__fp16)w2row.w;
    }

    // ray dir / origin (cam: uniform-address scalar loads)
    const float cd0 = cdirs[ray*3+0], cd1 = cdirs[ray*3+1], cd2 = cdirs[ray*3+2];
    const float rd0 = fmaf(cam[0], cd0, fmaf(cam[1], cd1, cam[2]*cd2));
    const float rd1 = fmaf(cam[4], cd0, fmaf(cam[5], cd1, cam[6]*cd2));
    const float rd2 = fmaf(cam[8], cd0, fmaf(cam[9], cd1, cam[10]*cd2));
    const float o0 = cam[3], o1 = cam[7], o2 = cam[11];

    // per-hidden-unit affine coeffs: pre_h(t) = A_h*t + B_h (h = lane)
    {
        const int h = lane;
        const float w10 = W1[0*HIDDEN+h], w11 = W1[1*HIDDEN+h], w12 = W1[2*HIDDEN+h];
        const float w13 = W1[3*HIDDEN+h], w14 = W1[4*HIDDEN+h], w15 = W1[5*HIDDEN+h];
        const float A = fmaf(rd0, w10, fmaf(rd1, w11, rd2*w12));
        float B = fmaf(o0, w10, fmaf(o1, w11, o2*w12));
        B = fmaf(rd0, w13, fmaf(rd1, w14, fmaf(rd2, w15, B))) + b1[h];
        Ahsh[wid][lane] = (__fp16)A;
        Bhsh[wid][lane] = (__fp16)B;
    }

    const float bin_dt = (Z_FAR - Z_NEAR) / (float)NUM_SAMPLES;
    const float uv = u[ray*NUM_SAMPLES + lane];             // coalesced
    const float t  = fmaf((float)lane + uv, bin_dt, Z_NEAR);
    tsh[wid][lane] = t;

    // hoisted fp16 coefficient pairs: h = kt*32 + grp*8 + 2q
    union { fp16x2 h2[4]; half8 h8; } aAh[2], aBh[2];
    #pragma unroll
    for (int kt = 0; kt < 2; ++kt) {
        const int h0 = kt*32 + grp*8;
        aAh[kt].h8 = *(const half8*)(&Ahsh[wid][h0]);
        aBh[kt].h8 = *(const half8*)(&Bhsh[wid][h0]);
    }

    // W-fragment (A-operand of swapped MFMA): W2T rows, zero for col>=4
    half8 bfrag[2] = {};
    if (col < 4) {
        bfrag[0] = *(const half8*)(&W2T[wid][col][grp*8]);
        bfrag[1] = *(const half8*)(&W2T[wid][col][32 + grp*8]);
    }
    const float b20 = b2[0], b21 = b2[1], b22 = b2[2], b23 = b2[3];

    const fp16x2 hzero = {(__fp16)0.0f, (__fp16)0.0f};

    // 4 M-tiles; A-frag build + 2 swapped MFMA; keep each tile's C in regs
    // (lanes 0-15: c[m][j] = output j of sample 16m+col). Also fetch tm and
    // t_{s+1} (adjacent LDS reads) for the composite.
    float4t cacc[4];
    float   tm[4], tnx[4];
    #pragma unroll
    for (int m = 0; m < 4; ++m) {
        tm[m]  = tsh[wid][col + 16*m];
        tnx[m] = tsh[wid][(col + 16*m + 1) & 63];
        const fp16x2 tvh = __builtin_amdgcn_cvt_pkrtz(tm[m], tm[m]);
        float4t c = {0.f, 0.f, 0.f, 0.f};
        #pragma unroll
        for (int kt = 0; kt < 2; ++kt) {
            union { fp16x2 h2[4]; half8 h8; } au;
            #pragma unroll
            for (int q = 0; q < 4; ++q) {
                const fp16x2 pre = __builtin_elementwise_fma(aAh[kt].h2[q], tvh, aBh[kt].h2[q]);
                au.h2[q] = __builtin_elementwise_max(pre, hzero);
            }
            c = __builtin_amdgcn_mfma_f32_16x16x32_f16(bfrag[kt], au.h8, c, 0, 0, 0);
        }
        cacc[m] = c;
    }

    // ---- composite on 16 lanes, 4 samples/lane (samples 16m+col) ----
    // per-sample lg = log2(1-alpha) = -density*sep*log2e
    float lg[4], alpha[4];
    #pragma unroll
    for (int m = 0; m < 4; ++m) {
        const float sep = (16*m + col < 63) ? (tnx[m] - tm[m]) : bin_dt;
        const float density = fmaxf(cacc[m][0] + b20, 0.0f);
        lg[m]    = -(density * sep) * LOG2E;
        alpha[m] = 1.0f - __builtin_amdgcn_exp2f(lg[m]);
    }

    // 4 independent 16-lane inclusive scans (short chains, ILP-4)
    float sc[4];
    #pragma unroll
    for (int m = 0; m < 4; ++m) sc[m] = row_scan_add(lg[m]);

    // block offsets: totals live in lane 15 of row 0
    const float tot0 = __int_as_float(__builtin_amdgcn_readlane(__float_as_int(sc[0]), 15));
    const float tot1 = __int_as_float(__builtin_amdgcn_readlane(__float_as_int(sc[1]), 15));
    const float tot2 = __int_as_float(__builtin_amdgcn_readlane(__float_as_int(sc[2]), 15));
    const float off1 = tot0, off2 = tot0 + tot1, off3 = off2 + tot2;

    // weights w = alpha * exp2(S_exclusive) ; S_excl = S_incl - lg
    float w[4];
    w[0] = alpha[0] * __builtin_amdgcn_exp2f(sc[0]          - lg[0]);
    w[1] = alpha[1] * __builtin_amdgcn_exp2f(sc[1] + off1   - lg[1]);
    w[2] = alpha[2] * __builtin_amdgcn_exp2f(sc[2] + off2   - lg[2]);
    w[3] = alpha[3] * __builtin_amdgcn_exp2f(sc[3] + off3   - lg[3]);

    // per-lane 4-term color partials, then 16-lane reductions
    float p0 = 0.f, p1 = 0.f, p2 = 0.f;
    #pragma unroll
    for (int m = 0; m < 4; ++m) {
        const float s1 = __builtin_amdgcn_rcpf(1.0f + __builtin_amdgcn_exp2f(-(cacc[m][1] + b21) * LOG2E));
        const float s2 = __builtin_amdgcn_rcpf(1.0f + __builtin_amdgcn_exp2f(-(cacc[m][2] + b22) * LOG2E));
        const float s3 = __builtin_amdgcn_rcpf(1.0f + __builtin_amdgcn_exp2f(-(cacc[m][3] + b23) * LOG2E));
        p0 = fmaf(w[m], s1, p0);
        p1 = fmaf(w[m], s2, p1);
        p2 = fmaf(w[m], s3, p2);
    }
    p0 = row_scan_add(p0);   // lane15 = total over 16 lanes
    p1 = row_scan_add(p1);
    p2 = row_scan_add(p2);

    if (lane == 15) {
        out[ray*3+0] = p0;
        out[ray*3+1] = p1;
        out[ray*3+2] = p2;
    }
}

extern "C" void kernel_launch(void* const* d_in, const int* in_sizes, int n_in,
                              void* d_out, int out_size, void* d_ws, size_t ws_size,
                              hipStream_t stream) {
    const float* cam   = (const float*)d_in[0];
    const float* u     = (const float*)d_in[1];
    const float* cdirs = (const float*)d_in[2];
    const float* W1    = (const float*)d_in[3];
    const float* b1    = (const float*)d_in[4];
    const float* W2    = (const float*)d_in[5];
    const float* b2    = (const float*)d_in[6];
    float* out = (float*)d_out;

    const int R = 256 * 256;
    dim3 grid(R / 4), block(256);
    render_kernel<<<grid, block, 0, stream>>>(cam, u, cdirs, W1, b1, W2, b2, out);
}

// Round 15
// 27.833 us; speedup vs baseline: 1.4262x; 1.4262x over previous
//
#include <hip/hip_runtime.h>

#define NUM_SAMPLES 64
#define HIDDEN 64
#define Z_NEAR 2.0f
#define Z_FAR 6.0f
#define LOG2E 1.44269504088896f

typedef _Float16 half8 __attribute__((ext_vector_type(8)));
typedef __fp16  fp16x2 __attribute__((ext_vector_type(2)));
typedef float   float4t __attribute__((ext_vector_type(4)));

// 6-step wave64 inclusive add-scan, pure VALU (DPP), zero LDS traffic.
template<int CTRL, int RMASK>
__device__ __forceinline__ float dpp_add(float x) {
    const int m = __builtin_amdgcn_update_dpp(0, __float_as_int(x), CTRL, RMASK, 0xf, true);
    return x + __int_as_float(m);
}
__device__ __forceinline__ float wave_scan_add(float x) {
    x = dpp_add<0x111, 0xf>(x);   // row_shr:1
    x = dpp_add<0x112, 0xf>(x);   // row_shr:2
    x = dpp_add<0x114, 0xf>(x);   // row_shr:4
    x = dpp_add<0x118, 0xf>(x);   // row_shr:8
    x = dpp_add<0x142, 0xa>(x);   // row_bcast:15 -> rows 1,3
    x = dpp_add<0x143, 0xc>(x);   // row_bcast:31 -> rows 2,3
    return x;                     // lane63 = full sum
}

// 16B-slot swizzle for C redistribution: <=2-way banks (free).
__device__ __forceinline__ int slot16(int s) { return 2*s + ((s>>2)&1); }

// R9 (28.2us, verified) x 2 SEQUENTIAL rays per wave, tsh KEPT (R13 showed
// removing it costs 1.6us). Front-end for BOTH rays hoisted to wave start:
// ray B's memory latency hides under ray A's compute; W2T/W1/cam/bfrag
// amortized over 2 rays. Compute phases strictly sequential (VGPR stays low,
// 8 waves/SIMD). Per-ray math byte-for-byte R9. No barriers.
__global__ __launch_bounds__(256) void render_kernel(
    const float* __restrict__ cam,    // 4x4
    const float* __restrict__ u,      // R x S
    const float* __restrict__ cdirs,  // R x 3
    const float* __restrict__ W1,     // 6 x 64
    const float* __restrict__ b1,     // 64
    const float* __restrict__ W2,     // 64 x 4
    const float* __restrict__ b2,     // 4
    float* __restrict__ out)          // R x 3
{
    const int lane = threadIdx.x & 63;
    const int wid  = threadIdx.x >> 6;
    const int grp  = lane >> 4;       // k-group
    const int col  = lane & 15;       // sample-in-tile
    const int rayA = blockIdx.x * 8 + wid * 2;
    const int rayB = rayA + 1;

    __shared__ __align__(16) __fp16 AhshA[4][HIDDEN];
    __shared__ __align__(16) __fp16 BhshA[4][HIDDEN];
    __shared__ __align__(16) __fp16 AhshB[4][HIDDEN];
    __shared__ __align__(16) __fp16 BhshB[4][HIDDEN];
    __shared__ __align__(16) float  tshA[4][NUM_SAMPLES];
    __shared__ __align__(16) float  tshB[4][NUM_SAMPLES];
    __shared__ __align__(16) __fp16 W2T[4][4][80];          // fp16 W2^T (ray-invariant)
    __shared__ __align__(16) float  cst[4][NUM_SAMPLES*8];  // reused A then B (lockstep-safe)

    // ---- hoisted front-end: all loads for both rays ----
    // per-wave fp16 W2^T staging (lane = hidden unit h)
    {
        const float4 w2row = ((const float4*)W2)[lane];
        W2T[wid][0][lane] = (__fp16)w2row.x;
        W2T[wid][1][lane] = (__fp16)w2row.y;
        W2T[wid][2][lane] = (__fp16)w2row.z;
        W2T[wid][3][lane] = (__fp16)w2row.w;
    }

    const float uvA = u[rayA*NUM_SAMPLES + lane];           // coalesced
    const float uvB = u[rayB*NUM_SAMPLES + lane];
    const float cdA0 = cdirs[rayA*3+0], cdA1 = cdirs[rayA*3+1], cdA2 = cdirs[rayA*3+2];
    const float cdB0 = cdirs[rayB*3+0], cdB1 = cdirs[rayB*3+1], cdB2 = cdirs[rayB*3+2];

    const float w10 = W1[0*HIDDEN+lane], w11 = W1[1*HIDDEN+lane], w12 = W1[2*HIDDEN+lane];
    const float w13 = W1[3*HIDDEN+lane], w14 = W1[4*HIDDEN+lane], w15 = W1[5*HIDDEN+lane];
    const float b1h = b1[lane];
    const float b20 = b2[0], b21 = b2[1], b22 = b2[2], b23 = b2[3];
    const float o0 = cam[3], o1 = cam[7], o2 = cam[11];

    // both rays' affine coeffs computed + staged up front
    {
        const float rdA0 = fmaf(cam[0], cdA0, fmaf(cam[1], cdA1, cam[2]*cdA2));
        const float rdA1 = fmaf(cam[4], cdA0, fmaf(cam[5], cdA1, cam[6]*cdA2));
        const float rdA2 = fmaf(cam[8], cdA0, fmaf(cam[9], cdA1, cam[10]*cdA2));
        const float AA = fmaf(rdA0, w10, fmaf(rdA1, w11, rdA2*w12));
        float BA = fmaf(o0, w10, fmaf(o1, w11, o2*w12));
        BA = fmaf(rdA0, w13, fmaf(rdA1, w14, fmaf(rdA2, w15, BA))) + b1h;
        AhshA[wid][lane] = (__fp16)AA;
        BhshA[wid][lane] = (__fp16)BA;

        const float rdB0 = fmaf(cam[0], cdB0, fmaf(cam[1], cdB1, cam[2]*cdB2));
        const float rdB1 = fmaf(cam[4], cdB0, fmaf(cam[5], cdB1, cam[6]*cdB2));
        const float rdB2 = fmaf(cam[8], cdB0, fmaf(cam[9], cdB1, cam[10]*cdB2));
        const float AB = fmaf(rdB0, w10, fmaf(rdB1, w11, rdB2*w12));
        float BB = fmaf(o0, w10, fmaf(o1, w11, o2*w12));
        BB = fmaf(rdB0, w13, fmaf(rdB1, w14, fmaf(rdB2, w15, BB))) + b1h;
        AhshB[wid][lane] = (__fp16)AB;
        BhshB[wid][lane] = (__fp16)BB;
    }

    const float bin_dt = (Z_FAR - Z_NEAR) / (float)NUM_SAMPLES;
    const float tA = fmaf((float)lane + uvA, bin_dt, Z_NEAR);
    const float tB = fmaf((float)lane + uvB, bin_dt, Z_NEAR);
    tshA[wid][lane] = tA;
    tshB[wid][lane] = tB;

    // W-fragment (A-operand of swapped MFMA), ray-invariant
    half8 bfrag[2] = {};
    if (col < 4) {
        bfrag[0] = *(const half8*)(&W2T[wid][col][grp*8]);
        bfrag[1] = *(const half8*)(&W2T[wid][col][32 + grp*8]);
    }

    const fp16x2 hzero = {(__fp16)0.0f, (__fp16)0.0f};
    union u8t { fp16x2 h2[4]; half8 h8; };

    float resA0, resA1, resA2, resB0, resB1, resB2;

    // ================= RAY A (byte-for-byte R9 body) =================
    {
        u8t aAh[2], aBh[2];
        #pragma unroll
        for (int kt = 0; kt < 2; ++kt) {
            const int h0 = kt*32 + grp*8;
            aAh[kt].h8 = *(const half8*)(&AhshA[wid][h0]);
            aBh[kt].h8 = *(const half8*)(&BhshA[wid][h0]);
        }
        const float tn  = tshA[wid][(lane+1) & 63];
        const float sep = (lane < NUM_SAMPLES-1) ? (tn - tA) : bin_dt;

        #pragma unroll
        for (int m = 0; m < 4; ++m) {
            const float tm = tshA[wid][col + 16*m];
            const fp16x2 tvh = __builtin_amdgcn_cvt_pkrtz(tm, tm);
            float4t c = {0.f, 0.f, 0.f, 0.f};
            #pragma unroll
            for (int kt = 0; kt < 2; ++kt) {
                u8t au;
                #pragma unroll
                for (int q = 0; q < 4; ++q) {
                    const fp16x2 pre = __builtin_elementwise_fma(aAh[kt].h2[q], tvh, aBh[kt].h2[q]);
                    au.h2[q] = __builtin_elementwise_max(pre, hzero);
                }
                c = __builtin_amdgcn_mfma_f32_16x16x32_f16(bfrag[kt], au.h8, c, 0, 0, 0);
            }
            if (lane < 16)
                *(float4t*)(&cst[wid][slot16(16*m + lane) * 4]) = c;
        }

        const float4t c4 = *(const float4t*)(&cst[wid][slot16(lane) * 4]);
        const float acc0 = c4[0] + b20, acc1 = c4[1] + b21;
        const float acc2 = c4[2] + b22, acc3 = c4[3] + b23;

        const float dsep  = fmaxf(acc0, 0.0f) * sep;
        const float lg    = -dsep * LOG2E;
        const float alpha = 1.0f - __builtin_amdgcn_exp2f(lg);
        const float S     = wave_scan_add(lg);
        const float T     = __builtin_amdgcn_exp2f(S - lg);
        const float w     = alpha * T;

        float c0 = w * __builtin_amdgcn_rcpf(1.0f + __builtin_amdgcn_exp2f(-acc1 * LOG2E));
        float c1 = w * __builtin_amdgcn_rcpf(1.0f + __builtin_amdgcn_exp2f(-acc2 * LOG2E));
        float c2 = w * __builtin_amdgcn_rcpf(1.0f + __builtin_amdgcn_exp2f(-acc3 * LOG2E));
        resA0 = wave_scan_add(c0);
        resA1 = wave_scan_add(c1);
        resA2 = wave_scan_add(c2);
    }

    // ================= RAY B (same body, B state) =================
    {
        u8t aAh[2], aBh[2];
        #pragma unroll
        for (int kt = 0; kt < 2; ++kt) {
            const int h0 = kt*32 + grp*8;
            aAh[kt].h8 = *(const half8*)(&AhshB[wid][h0]);
            aBh[kt].h8 = *(const half8*)(&BhshB[wid][h0]);
        }
        const float tn  = tshB[wid][(lane+1) & 63];
        const float sep = (lane < NUM_SAMPLES-1) ? (tn - tB) : bin_dt;

        #pragma unroll
        for (int m = 0; m < 4; ++m) {
            const float tm = tshB[wid][col + 16*m];
            const fp16x2 tvh = __builtin_amdgcn_cvt_pkrtz(tm, tm);
            float4t c = {0.f, 0.f, 0.f, 0.f};
            #pragma unroll
            for (int kt = 0; kt < 2; ++kt) {
                u8t au;
                #pragma unroll
                for (int q = 0; q < 4; ++q) {
                    const fp16x2 pre = __builtin_elementwise_fma(aAh[kt].h2[q], tvh, aBh[kt].h2[q]);
                    au.h2[q] = __builtin_elementwise_max(pre, hzero);
                }
                c = __builtin_amdgcn_mfma_f32_16x16x32_f16(bfrag[kt], au.h8, c, 0, 0, 0);
            }
            if (lane < 16)
                *(float4t*)(&cst[wid][slot16(16*m + lane) * 4]) = c;
        }

        const float4t c4 = *(const float4t*)(&cst[wid][slot16(lane) * 4]);
        const float acc0 = c4[0] + b20, acc1 = c4[1] + b21;
        const float acc2 = c4[2] + b22, acc3 = c4[3] + b23;

        const float dsep  = fmaxf(acc0, 0.0f) * sep;
        const float lg    = -dsep * LOG2E;
        const float alpha = 1.0f - __builtin_amdgcn_exp2f(lg);
        const float S     = wave_scan_add(lg);
        const float T     = __builtin_amdgcn_exp2f(S - lg);
        const float w     = alpha * T;

        float c0 = w * __builtin_amdgcn_rcpf(1.0f + __builtin_amdgcn_exp2f(-acc1 * LOG2E));
        float c1 = w * __builtin_amdgcn_rcpf(1.0f + __builtin_amdgcn_exp2f(-acc2 * LOG2E));
        float c2 = w * __builtin_amdgcn_rcpf(1.0f + __builtin_amdgcn_exp2f(-acc3 * LOG2E));
        resB0 = wave_scan_add(c0);
        resB1 = wave_scan_add(c1);
        resB2 = wave_scan_add(c2);
    }

    if (lane == 63) {
        out[rayA*3+0] = resA0;
        out[rayA*3+1] = resA1;
        out[rayA*3+2] = resA2;
        out[rayB*3+0] = resB0;
        out[rayB*3+1] = resB1;
        out[rayB*3+2] = resB2;
    }
}

extern "C" void kernel_launch(void* const* d_in, const int* in_sizes, int n_in,
                              void* d_out, int out_size, void* d_ws, size_t ws_size,
                              hipStream_t stream) {
    const float* cam   = (const float*)d_in[0];
    const float* u     = (const float*)d_in[1];
    const float* cdirs = (const float*)d_in[2];
    const float* W1    = (const float*)d_in[3];
    const float* b1    = (const float*)d_in[4];
    const float* W2    = (const float*)d_in[5];
    const float* b2    = (const float*)d_in[6];
    float* out = (float*)d_out;

    const int R = 256 * 256;
    dim3 grid(R / 8), block(256);   // 4 waves x 2 sequential rays per block
    render_kernel<<<grid, block, 0, stream>>>(cam, u, cdirs, W1, b1, W2, b2, out);
}